// Round 14
// baseline (99.086 us; speedup 1.0000x reference)
//
#include <hip/hip_runtime.h>

#define NN 8192
#define MM 8192
#define DD 256
#define NPART 8
#define MPART (MM / NPART)   // 1024
#define BK 64
#define NT (MPART / BK)      // 16

// (1/sqrt(256)) * log2(e) applied to raw fp8 logits inside exp2 (via fma)
#define SCALE_C 0.0901684403f
#define RAW_THR 127.5f

typedef short bf16x8 __attribute__((ext_vector_type(8)));
typedef float f32x4 __attribute__((ext_vector_type(4)));
typedef float f32x16 __attribute__((ext_vector_type(16)));
typedef unsigned int u32;
typedef u32 u32x2 __attribute__((ext_vector_type(2)));
typedef u32 u32x4 __attribute__((ext_vector_type(4)));

#define GLL16(src, dst) __builtin_amdgcn_global_load_lds( \
    (__attribute__((address_space(1))) void*)(src), \
    (__attribute__((address_space(3))) void*)(dst), 16, 0, 0)

static __device__ __forceinline__ unsigned char f2fp8(float a) {
    u32 r;
    asm("v_cvt_pk_fp8_f32 %0, %1, %1" : "=v"(r) : "v"(a));
    return (unsigned char)(r & 0xFFu);
}

static __device__ __forceinline__ u32 cvtpk(float lo, float hi) {
    u32 r;
    asm("v_cvt_pk_bf16_f32 %0, %1, %2" : "=v"(r) : "v"(lo), "v"(hi));
    return r;
}

// ---------------- projection v2: X staged once, W col-tiles double-buffered ----------------
// grid 256: bid 0..127 -> q rows (4 passes); bid 128..255 -> kv rows (8 passes: k ct0-3, v ct0-3)
// LDS: Xs 33KB + Ws[2] 66KB = 99KB (dynamic), 1 block/CU.
__global__ __launch_bounds__(256, 1) void proj_kernel(
    const float* __restrict__ xq, const float* __restrict__ xkv,
    const float* __restrict__ Wq, const float* __restrict__ bq,
    const float* __restrict__ Wk, const float* __restrict__ bk,
    const float* __restrict__ Wv, const float* __restrict__ bv,
    unsigned char* __restrict__ q8, unsigned char* __restrict__ k8,
    short* __restrict__ vp)
{
    extern __shared__ short plds[];
    short (*Xs)[264] = (short(*)[264])plds;                       // [64][264]
    short (*Ws)[64][264] = (short(*)[64][264])(plds + 16896);     // [2][64][264]

    const int bid = blockIdx.x;
    const int iskv = bid >> 7;
    const int rt = bid & 127;
    const float* __restrict__ X = iskv ? xkv : xq;
    const float* __restrict__ W0 = iskv ? Wk : Wq;
    const int npass = iskv ? 8 : 4;

    const int tid = threadIdx.x;
    const int lane = tid & 63;
    const int wv = tid >> 6;
    const int l15 = lane & 15;
    const int lg = lane >> 4;

    // stage X (once) and W pass-0 (ct=0)
    #pragma unroll
    for (int i = 0; i < 16; ++i) {
        int c = i * 256 + tid;
        int row = c >> 6;
        int col4 = (c & 63) << 2;
        f32x4 xv = *reinterpret_cast<const f32x4*>(X + (size_t)(rt * 64 + row) * DD + col4);
        f32x4 wr = *reinterpret_cast<const f32x4*>(W0 + (size_t)row * DD + col4);
        u32x2 xb, wb;
        xb[0] = cvtpk(xv[0], xv[1]); xb[1] = cvtpk(xv[2], xv[3]);
        wb[0] = cvtpk(wr[0], wr[1]); wb[1] = cvtpk(wr[2], wr[3]);
        *reinterpret_cast<u32x2*>(&Xs[row][col4]) = xb;
        *reinterpret_cast<u32x2*>(&Ws[0][row][col4]) = wb;
    }
    __syncthreads();

    #pragma unroll 1
    for (int pass = 0; pass < npass; ++pass) {
        const int cur = pass & 1;
        // stage next W col-tile into the other buffer (overlaps compute)
        if (pass + 1 < npass) {
            const int np = pass + 1;
            const float* __restrict__ Wn = iskv ? ((np < 4) ? Wk : Wv) : Wq;
            const int nct = np & 3;
            #pragma unroll
            for (int i = 0; i < 16; ++i) {
                int c = i * 256 + tid;
                int row = c >> 6;
                int col4 = (c & 63) << 2;
                f32x4 wr = *reinterpret_cast<const f32x4*>(Wn + (size_t)(nct * 64 + row) * DD + col4);
                u32x2 wb;
                wb[0] = cvtpk(wr[0], wr[1]); wb[1] = cvtpk(wr[2], wr[3]);
                *reinterpret_cast<u32x2*>(&Ws[cur ^ 1][row][col4]) = wb;
            }
        }

        f32x4 acc[4];
        #pragma unroll
        for (int f = 0; f < 4; ++f) acc[f] = f32x4{0.f, 0.f, 0.f, 0.f};
        #pragma unroll
        for (int kk = 0; kk < 8; ++kk) {
            bf16x8 a = *reinterpret_cast<const bf16x8*>(&Xs[wv * 16 + l15][kk * 32 + lg * 8]);
            #pragma unroll
            for (int f = 0; f < 4; ++f) {
                bf16x8 b = *reinterpret_cast<const bf16x8*>(&Ws[cur][f * 16 + l15][kk * 32 + lg * 8]);
                acc[f] = __builtin_amdgcn_mfma_f32_16x16x32_bf16(a, b, acc[f], 0, 0, 0);
            }
        }

        const int ct = pass & 3;
        if (!iskv) {
            #pragma unroll
            for (int f = 0; f < 4; ++f) {
                const int o = ct * 64 + f * 16 + l15;
                const float bsv = bq[o];
                #pragma unroll
                for (int r = 0; r < 4; ++r) {
                    const int rowg = rt * 64 + wv * 16 + lg * 4 + r;
                    q8[(size_t)rowg * DD + o] = f2fp8(acc[f][r] + bsv);
                }
            }
        } else if (pass < 4) {
            #pragma unroll
            for (int f = 0; f < 4; ++f) {
                const int o = ct * 64 + f * 16 + l15;
                const float bsv = bk[o];
                #pragma unroll
                for (int r = 0; r < 4; ++r) {
                    const int rowg = rt * 64 + wv * 16 + lg * 4 + r;
                    k8[(size_t)(o >> 3) * (MM * 8) + (size_t)rowg * 8 + (o & 7)] = f2fp8(acc[f][r] + bsv);
                }
            }
        } else {
            #pragma unroll
            for (int f = 0; f < 4; ++f) {
                const int o = ct * 64 + f * 16 + l15;
                const float bsv = bv[o];
                const int mb = rt * 64 + wv * 16 + lg * 4;
                u32x2 pk;
                pk[0] = cvtpk(acc[f][0] + bsv, acc[f][1] + bsv);
                pk[1] = cvtpk(acc[f][2] + bsv, acc[f][3] + bsv);
                *reinterpret_cast<u32x2*>(&vp[(size_t)(mb >> 6) * 16384 + o * 64 + (mb & 63)]) = pk;
            }
        }
        __syncthreads();
    }
}

// ---------------- flash attention: pipelined QK(t) || PV(t-1) [frozen from R13] ----------------
// grid 256 = 32 q-tiles x 8 parts; 512 threads (8 waves x 32 q/wave)
// LDS: 3x16KB K(fp8 plane-major) + 3x32KB V(bf16) = 144 KB.
__global__ __launch_bounds__(512, 2) void attn_kernel(
    const unsigned char* __restrict__ qg, const unsigned char* __restrict__ kg,
    const short* __restrict__ vp, short* __restrict__ outpB,
    float* __restrict__ statm, float* __restrict__ statl)
{
    extern __shared__ short lds[];
    short* KsBase = lds;                 // 3 x 8192 shorts
    short* VsBase = lds + 3 * 8192;      // 3 x 16384 shorts

    const int bid = blockIdx.x;
    const int p = bid & 7;
    const int qt = bid >> 3;
    const int q0 = qt * 256;
    const int tile0 = p * NT;

    const int tid = threadIdx.x;
    const int lane = tid & 63;
    const int w = tid >> 6;
    const int l31 = lane & 31;
    const int h = lane >> 5;

    long qf8[16];
    {
        const unsigned char* qr = qg + (size_t)(q0 + w * 32 + l31) * DD + h * 8;
        #pragma unroll
        for (int kt = 0; kt < 16; ++kt)
            qf8[kt] = __builtin_bit_cast(long, *reinterpret_cast<const u32x2*>(qr + kt * 16));
    }

    int koff[2], jdstK[2], voff[4], jdstV[4];
    #pragma unroll
    for (int i = 0; i < 2; ++i) {
        const int j = w * 2 + i;
        const int pl = 2 * j + (lane >> 5);
        koff[i] = pl * (MM * 8) + (lane & 31) * 16;
        jdstK[i] = __builtin_amdgcn_readfirstlane(j * 512);
    }
    #pragma unroll
    for (int i = 0; i < 4; ++i) {
        const int j = w * 4 + i;
        const int d = j * 8 + (lane >> 3);
        const int cl = ((lane & 7) - (d & 7)) & 7;
        voff[i] = d * 64 + (cl << 3);
        jdstV[i] = __builtin_amdgcn_readfirstlane(j * 512);
    }

    f32x16 o[8];
    #pragma unroll
    for (int dt = 0; dt < 8; ++dt)
        #pragma unroll
        for (int i = 0; i < 16; ++i) o[dt][i] = 0.f;
    float mrun = -1e30f, lrun = 0.f;
    bf16x8 pb[4];

    #pragma unroll
    for (int i = 0; i < 2; ++i)
        GLL16(kg + (size_t)tile0 * 512 + koff[i], KsBase + jdstK[i]);
    #pragma unroll
    for (int i = 0; i < 4; ++i)
        GLL16(vp + (size_t)tile0 * 16384 + voff[i], VsBase + jdstV[i]);
    #pragma unroll
    for (int i = 0; i < 2; ++i)
        GLL16(kg + (size_t)(tile0 + 1) * 512 + koff[i], KsBase + 8192 + jdstK[i]);
    asm volatile("s_waitcnt vmcnt(6)\n\ts_barrier" ::: "memory");

    // ================= t = 0 (peeled: QK only) =================
    {
        const char* kb = (const char*)KsBase;
        #pragma unroll
        for (int i = 0; i < 4; ++i)
            GLL16(vp + (size_t)(tile0 + 1) * 16384 + voff[i], VsBase + 16384 + jdstV[i]);
        #pragma unroll
        for (int i = 0; i < 2; ++i)
            GLL16(kg + (size_t)(tile0 + 2) * 512 + koff[i], KsBase + 2 * 8192 + jdstK[i]);

        f32x16 sL, sH;
        #pragma unroll
        for (int i = 0; i < 16; ++i) { sL[i] = 0.f; sH[i] = 0.f; }
        __builtin_amdgcn_s_setprio(1);
        #pragma unroll
        for (int kt = 0; kt < 16; ++kt) {
            const int gb = (kt * 2 + h) * 512 + l31 * 8;
            long aL = __builtin_bit_cast(long, *reinterpret_cast<const u32x2*>(kb + gb));
            long aH = __builtin_bit_cast(long, *reinterpret_cast<const u32x2*>(kb + gb + 256));
            sL = __builtin_amdgcn_mfma_f32_32x32x16_fp8_fp8(aL, qf8[kt], sL, 0, 0, 0);
            sH = __builtin_amdgcn_mfma_f32_32x32x16_fp8_fp8(aH, qf8[kt], sH, 0, 0, 0);
        }
        __builtin_amdgcn_s_setprio(0);

        float mx;
        {
            float a0 = fmaxf(fmaxf(sL[0], sL[1]), fmaxf(sL[2], sL[3]));
            float a1 = fmaxf(fmaxf(sL[4], sL[5]), fmaxf(sL[6], sL[7]));
            float a2 = fmaxf(fmaxf(sL[8], sL[9]), fmaxf(sL[10], sL[11]));
            float a3 = fmaxf(fmaxf(sL[12], sL[13]), fmaxf(sL[14], sL[15]));
            float b0 = fmaxf(fmaxf(sH[0], sH[1]), fmaxf(sH[2], sH[3]));
            float b1 = fmaxf(fmaxf(sH[4], sH[5]), fmaxf(sH[6], sH[7]));
            float b2 = fmaxf(fmaxf(sH[8], sH[9]), fmaxf(sH[10], sH[11]));
            float b3 = fmaxf(fmaxf(sH[12], sH[13]), fmaxf(sH[14], sH[15]));
            mx = fmaxf(fmaxf(fmaxf(a0, a1), fmaxf(a2, a3)),
                       fmaxf(fmaxf(b0, b1), fmaxf(b2, b3)));
            mx = fmaxf(mx, __shfl_xor(mx, 32));
        }
        mrun = mx;
        const float msc = -mrun * SCALE_C;
        #pragma unroll
        for (int i = 0; i < 16; ++i) {
            sL[i] = __builtin_amdgcn_exp2f(fmaf(sL[i], SCALE_C, msc));
            sH[i] = __builtin_amdgcn_exp2f(fmaf(sH[i], SCALE_C, msc));
        }
        {
            float r0 = ((sL[0] + sL[1]) + (sL[2] + sL[3])) + ((sL[4] + sL[5]) + (sL[6] + sL[7]));
            float r1 = ((sL[8] + sL[9]) + (sL[10] + sL[11])) + ((sL[12] + sL[13]) + (sL[14] + sL[15]));
            float r2 = ((sH[0] + sH[1]) + (sH[2] + sH[3])) + ((sH[4] + sH[5]) + (sH[6] + sH[7]));
            float r3 = ((sH[8] + sH[9]) + (sH[10] + sH[11])) + ((sH[12] + sH[13]) + (sH[14] + sH[15]));
            float rs = (r0 + r1) + (r2 + r3);
            rs += __shfl_xor(rs, 32);
            lrun += rs;
        }
        #pragma unroll
        for (int half = 0; half < 2; ++half) {
            const f32x16& sv = half ? sH : sL;
            #pragma unroll
            for (int g = 0; g < 2; ++g) {
                u32 pa = cvtpk(sv[g * 8 + 0], sv[g * 8 + 1]);
                u32 pbq = cvtpk(sv[g * 8 + 2], sv[g * 8 + 3]);
                u32 pc = cvtpk(sv[g * 8 + 4], sv[g * 8 + 5]);
                u32 pd = cvtpk(sv[g * 8 + 6], sv[g * 8 + 7]);
                const u32 xa = (u32)__shfl_xor((int)pa, 32);
                const u32 xb = (u32)__shfl_xor((int)pbq, 32);
                const u32 xc = (u32)__shfl_xor((int)pc, 32);
                const u32 xd = (u32)__shfl_xor((int)pd, 32);
                u32x4 bb;
                bb[0] = h ? xc : pa;
                bb[1] = h ? xd : pbq;
                bb[2] = h ? pc : xa;
                bb[3] = h ? pd : xb;
                pb[half * 2 + g] = __builtin_bit_cast(bf16x8, bb);
            }
        }
        asm volatile("s_waitcnt vmcnt(6)\n\ts_barrier" ::: "memory");
    }

    // ================= main loop t = 1 .. NT-1 =================
    int cur = 1;
    #pragma unroll 1
    for (int t = 1; t < NT; ++t) {
        const char* kb = (const char*)(KsBase + cur * 8192);
        const int vprev = (cur == 0) ? 2 : cur - 1;
        const char* vbp = (const char*)(VsBase + vprev * 16384);

        if (t + 1 < NT) {
            const int vw = (cur == 2) ? 0 : cur + 1;
            const size_t tb = (size_t)(tile0 + t + 1) * 16384;
            short* vd = VsBase + vw * 16384;
            #pragma unroll
            for (int i = 0; i < 4; ++i) GLL16(vp + tb + voff[i], vd + jdstV[i]);
        }
        if (t + 2 < NT) {
            const size_t tb = (size_t)(tile0 + t + 2) * 512;
            short* kd = KsBase + vprev * 8192;
            #pragma unroll
            for (int i = 0; i < 2; ++i) GLL16(kg + tb + koff[i], kd + jdstK[i]);
        }

        f32x16 sL, sH;
        #pragma unroll
        for (int i = 0; i < 16; ++i) { sL[i] = 0.f; sH[i] = 0.f; }
        __builtin_amdgcn_s_setprio(1);
        #pragma unroll
        for (int kt = 0; kt < 16; ++kt) {
            const int gb = (kt * 2 + h) * 512 + l31 * 8;
            long aL = __builtin_bit_cast(long, *reinterpret_cast<const u32x2*>(kb + gb));
            long aH = __builtin_bit_cast(long, *reinterpret_cast<const u32x2*>(kb + gb + 256));
            sL = __builtin_amdgcn_mfma_f32_32x32x16_fp8_fp8(aL, qf8[kt], sL, 0, 0, 0);
            sH = __builtin_amdgcn_mfma_f32_32x32x16_fp8_fp8(aH, qf8[kt], sH, 0, 0, 0);
            {
                const int j = 2 * kt;
                const int dt = j & 7, ks = j >> 3;
                const int d = dt * 32 + l31;
                bf16x8 av = *reinterpret_cast<const bf16x8*>(
                    vbp + d * 128 + (((2 * ks + h + (d & 7)) & 7) << 4));
                o[dt] = __builtin_amdgcn_mfma_f32_32x32x16_bf16(av, pb[ks], o[dt], 0, 0, 0);
            }
            {
                const int j = 2 * kt + 1;
                const int dt = j & 7, ks = j >> 3;
                const int d = dt * 32 + l31;
                bf16x8 av = *reinterpret_cast<const bf16x8*>(
                    vbp + d * 128 + (((2 * ks + h + (d & 7)) & 7) << 4));
                o[dt] = __builtin_amdgcn_mfma_f32_32x32x16_bf16(av, pb[ks], o[dt], 0, 0, 0);
            }
        }
        __builtin_amdgcn_s_setprio(0);

        float mx;
        {
            float a0 = fmaxf(fmaxf(sL[0], sL[1]), fmaxf(sL[2], sL[3]));
            float a1 = fmaxf(fmaxf(sL[4], sL[5]), fmaxf(sL[6], sL[7]));
            float a2 = fmaxf(fmaxf(sL[8], sL[9]), fmaxf(sL[10], sL[11]));
            float a3 = fmaxf(fmaxf(sL[12], sL[13]), fmaxf(sL[14], sL[15]));
            float b0 = fmaxf(fmaxf(sH[0], sH[1]), fmaxf(sH[2], sH[3]));
            float b1 = fmaxf(fmaxf(sH[4], sH[5]), fmaxf(sH[6], sH[7]));
            float b2 = fmaxf(fmaxf(sH[8], sH[9]), fmaxf(sH[10], sH[11]));
            float b3 = fmaxf(fmaxf(sH[12], sH[13]), fmaxf(sH[14], sH[15]));
            mx = fmaxf(fmaxf(fmaxf(a0, a1), fmaxf(a2, a3)),
                       fmaxf(fmaxf(b0, b1), fmaxf(b2, b3)));
            mx = fmaxf(mx, __shfl_xor(mx, 32));
        }
        if (__any(mx > mrun + RAW_THR)) {
            const float mn = fmaxf(mrun, mx);
            const float al = __builtin_amdgcn_exp2f((mrun - mn) * SCALE_C);
            mrun = mn;
            lrun *= al;
            #pragma unroll
            for (int dt = 0; dt < 8; ++dt)
                #pragma unroll
                for (int i = 0; i < 16; ++i) o[dt][i] *= al;
        }
        const float msc = -mrun * SCALE_C;
        #pragma unroll
        for (int i = 0; i < 16; ++i) {
            sL[i] = __builtin_amdgcn_exp2f(fmaf(sL[i], SCALE_C, msc));
            sH[i] = __builtin_amdgcn_exp2f(fmaf(sH[i], SCALE_C, msc));
        }
        {
            float r0 = ((sL[0] + sL[1]) + (sL[2] + sL[3])) + ((sL[4] + sL[5]) + (sL[6] + sL[7]));
            float r1 = ((sL[8] + sL[9]) + (sL[10] + sL[11])) + ((sL[12] + sL[13]) + (sL[14] + sL[15]));
            float r2 = ((sH[0] + sH[1]) + (sH[2] + sH[3])) + ((sH[4] + sH[5]) + (sH[6] + sH[7]));
            float r3 = ((sH[8] + sH[9]) + (sH[10] + sH[11])) + ((sH[12] + sH[13]) + (sH[14] + sH[15]));
            float rs = (r0 + r1) + (r2 + r3);
            rs += __shfl_xor(rs, 32);
            lrun += rs;
        }
        #pragma unroll
        for (int half = 0; half < 2; ++half) {
            const f32x16& sv = half ? sH : sL;
            #pragma unroll
            for (int g = 0; g < 2; ++g) {
                u32 pa = cvtpk(sv[g * 8 + 0], sv[g * 8 + 1]);
                u32 pbq = cvtpk(sv[g * 8 + 2], sv[g * 8 + 3]);
                u32 pc = cvtpk(sv[g * 8 + 4], sv[g * 8 + 5]);
                u32 pd = cvtpk(sv[g * 8 + 6], sv[g * 8 + 7]);
                const u32 xa = (u32)__shfl_xor((int)pa, 32);
                const u32 xb = (u32)__shfl_xor((int)pbq, 32);
                const u32 xc = (u32)__shfl_xor((int)pc, 32);
                const u32 xd = (u32)__shfl_xor((int)pd, 32);
                u32x4 bb;
                bb[0] = h ? xc : pa;
                bb[1] = h ? xd : pbq;
                bb[2] = h ? pc : xa;
                bb[3] = h ? pd : xb;
                pb[half * 2 + g] = __builtin_bit_cast(bf16x8, bb);
            }
        }

        if (t + 2 < NT) {
            asm volatile("s_waitcnt vmcnt(6)\n\ts_barrier" ::: "memory");
        } else if (t + 1 < NT) {
            asm volatile("s_waitcnt vmcnt(4)\n\ts_barrier" ::: "memory");
        } else {
            asm volatile("s_waitcnt vmcnt(0)\n\ts_barrier" ::: "memory");
        }
        cur = (cur == 2) ? 0 : cur + 1;
    }

    // ---- final PV(NT-1) ----
    {
        const char* vb = (const char*)(VsBase + ((NT - 1) % 3) * 16384);
        __builtin_amdgcn_s_setprio(1);
        #pragma unroll
        for (int dt = 0; dt < 8; ++dt) {
            const int d = dt * 32 + l31;
            const char* rbase = vb + d * 128;
            const int rot = d & 7;
            bf16x8 a0 = *reinterpret_cast<const bf16x8*>(rbase + (((0 + h + rot) & 7) << 4));
            bf16x8 a1 = *reinterpret_cast<const bf16x8*>(rbase + (((2 + h + rot) & 7) << 4));
            bf16x8 a2 = *reinterpret_cast<const bf16x8*>(rbase + (((4 + h + rot) & 7) << 4));
            bf16x8 a3 = *reinterpret_cast<const bf16x8*>(rbase + (((6 + h + rot) & 7) << 4));
            o[dt] = __builtin_amdgcn_mfma_f32_32x32x16_bf16(a0, pb[0], o[dt], 0, 0, 0);
            o[dt] = __builtin_amdgcn_mfma_f32_32x32x16_bf16(a1, pb[1], o[dt], 0, 0, 0);
            o[dt] = __builtin_amdgcn_mfma_f32_32x32x16_bf16(a2, pb[2], o[dt], 0, 0, 0);
            o[dt] = __builtin_amdgcn_mfma_f32_32x32x16_bf16(a3, pb[3], o[dt], 0, 0, 0);
        }
        __builtin_amdgcn_s_setprio(0);
    }

    const int qc = q0 + w * 32 + l31;
    #pragma unroll
    for (int dt = 0; dt < 8; ++dt) {
        #pragma unroll
        for (int i = 0; i < 16; i += 2) {
            const u32 two = cvtpk(o[dt][i], o[dt][i + 1]);
            const int dg = dt * 32 + (i & 3) + 8 * (i >> 2) + 4 * h;
            outpB[((size_t)p * DD + dg) * NN + qc] = (short)(two & 0xFFFFu);
            outpB[((size_t)p * DD + dg + 1) * NN + qc] = (short)(two >> 16);
        }
    }
    if (h == 0) {
        statm[(size_t)p * NN + qc] = mrun;
        statl[(size_t)p * NN + qc] = lrun;
    }
}

// ---------------- combine [frozen from R13] ----------------
__global__ __launch_bounds__(1024) void combine_kernel(
    const short* __restrict__ outpB, const float* __restrict__ statm,
    const float* __restrict__ statl, float* __restrict__ out)
{
    __shared__ float Wn[NPART][64];
    __shared__ float Ot[64][DD + 2];

    const int q0 = blockIdx.x * 64;
    const int tid = threadIdx.x;

    if (tid < 64) {
        const int q = q0 + tid;
        float mv[NPART], lv[NPART];
        float mM = -1e30f;
        #pragma unroll
        for (int p = 0; p < NPART; ++p) {
            mv[p] = statm[(size_t)p * NN + q];
            lv[p] = statl[(size_t)p * NN + q];
            mM = fmaxf(mM, mv[p]);
        }
        float L = 0.f;
        float wg[NPART];
        #pragma unroll
        for (int p = 0; p < NPART; ++p) {
            wg[p] = exp2f((mv[p] - mM) * SCALE_C);
            L += wg[p] * lv[p];
        }
        const float inv = 1.0f / L;
        #pragma unroll
        for (int p = 0; p < NPART; ++p) Wn[p][tid] = wg[p] * inv;
    }
    __syncthreads();

    {
        const int pr = tid & 31;
        const int d0 = tid >> 5;
        #pragma unroll 2
        for (int d = d0; d < DD; d += 32) {
            float a0 = 0.f, a1 = 0.f;
            #pragma unroll
            for (int p = 0; p < NPART; ++p) {
                const u32 two = *reinterpret_cast<const u32*>(
                    &outpB[((size_t)p * DD + d) * NN + q0 + pr * 2]);
                a0 += Wn[p][pr * 2] * __builtin_bit_cast(float, two << 16);
                a1 += Wn[p][pr * 2 + 1] * __builtin_bit_cast(float, two & 0xFFFF0000u);
            }
            Ot[pr * 2][d] = a0;
            Ot[pr * 2 + 1][d] = a1;
        }
    }
    __syncthreads();

    {
        const int qq = tid >> 4;
        const int c = tid & 15;
        #pragma unroll
        for (int j = 0; j < 4; ++j) {
            const int d = c * 16 + j * 4;
            *reinterpret_cast<f32x4*>(&out[(size_t)(q0 + qq) * DD + d]) =
                *reinterpret_cast<const f32x4*>(&Ot[qq][d]);
        }
    }
}

extern "C" void kernel_launch(void* const* d_in, const int* in_sizes, int n_in,
                              void* d_out, int out_size, void* d_ws, size_t ws_size,
                              hipStream_t stream) {
    const float* xq  = (const float*)d_in[0];
    const float* xkv = (const float*)d_in[1];
    const float* Wq  = (const float*)d_in[2];
    const float* bq  = (const float*)d_in[3];
    const float* Wk  = (const float*)d_in[4];
    const float* bk  = (const float*)d_in[5];
    const float* Wv  = (const float*)d_in[6];
    const float* bv  = (const float*)d_in[7];
    float* out = (float*)d_out;

    char* ws = (char*)d_ws;
    unsigned char* qb8 = (unsigned char*)(ws);
    unsigned char* kb8 = (unsigned char*)(ws + ((size_t)4 << 20));
    short* vpb = (short*)(ws + ((size_t)8 << 20));
    short* outpB = (short*)(ws + ((size_t)12 << 20));
    float* sm = (float*)(ws + ((size_t)12 << 20) + (size_t)NPART * NN * DD * 2);
    float* sl = sm + (size_t)NPART * NN;

    hipFuncSetAttribute(reinterpret_cast<const void*>(proj_kernel),
                        hipFuncAttributeMaxDynamicSharedMemorySize, 101376);
    hipFuncSetAttribute(reinterpret_cast<const void*>(attn_kernel),
                        hipFuncAttributeMaxDynamicSharedMemorySize, 147456);

    proj_kernel<<<256, 256, 101376, stream>>>(xq, xkv, Wq, bq, Wk, bk, Wv, bv, qb8, kb8, vpb);
    attn_kernel<<<256, 512, 147456, stream>>>(qb8, kb8, vpb, outpB, sm, sl);
    combine_kernel<<<NN / 64, 1024, 0, stream>>>(outpB, sm, sl, out);
}

// Round 15
// 97.014 us; speedup vs baseline: 1.0214x; 1.0214x over previous
//
#include <hip/hip_runtime.h>

#define NN 8192
#define MM 8192
#define DD 256
#define NPART 8
#define MPART (MM / NPART)   // 1024
#define BK 64
#define NT (MPART / BK)      // 16

// (1/sqrt(256)) * log2(e) applied to raw fp8 logits inside exp2 (via fma)
#define SCALE_C 0.0901684403f
#define RAW_THR 127.5f

typedef short bf16x8 __attribute__((ext_vector_type(8)));
typedef float f32x4 __attribute__((ext_vector_type(4)));
typedef float f32x16 __attribute__((ext_vector_type(16)));
typedef unsigned int u32;
typedef u32 u32x2 __attribute__((ext_vector_type(2)));
typedef u32 u32x4 __attribute__((ext_vector_type(4)));

#define GLL16(src, dst) __builtin_amdgcn_global_load_lds( \
    (__attribute__((address_space(1))) void*)(src), \
    (__attribute__((address_space(3))) void*)(dst), 16, 0, 0)

static __device__ __forceinline__ unsigned char f2fp8(float a) {
    u32 r;
    asm("v_cvt_pk_fp8_f32 %0, %1, %1" : "=v"(r) : "v"(a));
    return (unsigned char)(r & 0xFFu);
}

static __device__ __forceinline__ u32 cvtpk(float lo, float hi) {
    u32 r;
    asm("v_cvt_pk_bf16_f32 %0, %1, %2" : "=v"(r) : "v"(lo), "v"(hi));
    return r;
}

// ---------------- projection (R12/R13 best-measured version) ----------------
// grid 1024: bid<512 -> q (fp8 raw); bid>=512 -> fused k(fp8 plane-major) + v(bf16 panels)
__global__ __launch_bounds__(256, 2) void proj_kernel(
    const float* __restrict__ xq, const float* __restrict__ xkv,
    const float* __restrict__ Wq, const float* __restrict__ bq,
    const float* __restrict__ Wk, const float* __restrict__ bk,
    const float* __restrict__ Wv, const float* __restrict__ bv,
    unsigned char* __restrict__ q8, unsigned char* __restrict__ k8,
    short* __restrict__ vp)
{
    __shared__ short Xs[64][264];
    __shared__ short Ws[64][264];

    const int bid = blockIdx.x;
    const int iskv = bid >> 9;
    const int t = bid & 511;
    const int rt = t >> 2;
    const int ct = t & 3;
    const float* __restrict__ X = iskv ? xkv : xq;
    const float* __restrict__ W1 = iskv ? Wk : Wq;

    const int tid = threadIdx.x;
    const int lane = tid & 63;
    const int wv = tid >> 6;
    const int l15 = lane & 15;
    const int lg = lane >> 4;

    #pragma unroll
    for (int i = 0; i < 16; ++i) {
        int c = i * 256 + tid;
        int row = c >> 6;
        int col4 = (c & 63) << 2;
        f32x4 xv = *reinterpret_cast<const f32x4*>(X + (size_t)(rt * 64 + row) * DD + col4);
        f32x4 wr = *reinterpret_cast<const f32x4*>(W1 + (size_t)(ct * 64 + row) * DD + col4);
        u32x2 xb, wb;
        xb[0] = cvtpk(xv[0], xv[1]); xb[1] = cvtpk(xv[2], xv[3]);
        wb[0] = cvtpk(wr[0], wr[1]); wb[1] = cvtpk(wr[2], wr[3]);
        *reinterpret_cast<u32x2*>(&Xs[row][col4]) = xb;
        *reinterpret_cast<u32x2*>(&Ws[row][col4]) = wb;
    }
    __syncthreads();

    f32x4 acc[4];
    #pragma unroll
    for (int f = 0; f < 4; ++f) acc[f] = f32x4{0.f, 0.f, 0.f, 0.f};

    #pragma unroll
    for (int kk = 0; kk < 8; ++kk) {
        bf16x8 a = *reinterpret_cast<const bf16x8*>(&Xs[wv * 16 + l15][kk * 32 + lg * 8]);
        #pragma unroll
        for (int f = 0; f < 4; ++f) {
            bf16x8 b = *reinterpret_cast<const bf16x8*>(&Ws[f * 16 + l15][kk * 32 + lg * 8]);
            acc[f] = __builtin_amdgcn_mfma_f32_16x16x32_bf16(a, b, acc[f], 0, 0, 0);
        }
    }

    if (!iskv) {
        #pragma unroll
        for (int f = 0; f < 4; ++f) {
            const int o = ct * 64 + f * 16 + l15;
            const float bsv = bq[o];
            #pragma unroll
            for (int r = 0; r < 4; ++r) {
                const int rowg = rt * 64 + wv * 16 + lg * 4 + r;
                q8[(size_t)rowg * DD + o] = f2fp8(acc[f][r] + bsv);
            }
        }
        return;
    }

    #pragma unroll
    for (int f = 0; f < 4; ++f) {
        const int o = ct * 64 + f * 16 + l15;
        const float bsv = bk[o];
        #pragma unroll
        for (int r = 0; r < 4; ++r) {
            const int rowg = rt * 64 + wv * 16 + lg * 4 + r;
            k8[(size_t)(o >> 3) * (MM * 8) + (size_t)rowg * 8 + (o & 7)] = f2fp8(acc[f][r] + bsv);
        }
    }

    __syncthreads();
    #pragma unroll
    for (int i = 0; i < 16; ++i) {
        int c = i * 256 + tid;
        int row = c >> 6;
        int col4 = (c & 63) << 2;
        f32x4 wr = *reinterpret_cast<const f32x4*>(Wv + (size_t)(ct * 64 + row) * DD + col4);
        u32x2 wb;
        wb[0] = cvtpk(wr[0], wr[1]); wb[1] = cvtpk(wr[2], wr[3]);
        *reinterpret_cast<u32x2*>(&Ws[row][col4]) = wb;
    }
    __syncthreads();

    #pragma unroll
    for (int f = 0; f < 4; ++f) acc[f] = f32x4{0.f, 0.f, 0.f, 0.f};
    #pragma unroll
    for (int kk = 0; kk < 8; ++kk) {
        bf16x8 a = *reinterpret_cast<const bf16x8*>(&Xs[wv * 16 + l15][kk * 32 + lg * 8]);
        #pragma unroll
        for (int f = 0; f < 4; ++f) {
            bf16x8 b = *reinterpret_cast<const bf16x8*>(&Ws[f * 16 + l15][kk * 32 + lg * 8]);
            acc[f] = __builtin_amdgcn_mfma_f32_16x16x32_bf16(a, b, acc[f], 0, 0, 0);
        }
    }
    #pragma unroll
    for (int f = 0; f < 4; ++f) {
        const int o = ct * 64 + f * 16 + l15;
        const float bsv = bv[o];
        const int mb = rt * 64 + wv * 16 + lg * 4;
        u32x2 pk;
        pk[0] = cvtpk(acc[f][0] + bsv, acc[f][1] + bsv);
        pk[1] = cvtpk(acc[f][2] + bsv, acc[f][3] + bsv);
        *reinterpret_cast<u32x2*>(&vp[(size_t)(mb >> 6) * 16384 + o * 64 + (mb & 63)]) = pk;
    }
}

// ---------------- flash attention: pipelined QK(t) || PV(t-1) [frozen R13] ----------------
// grid 256 = 32 q-tiles x 8 parts; 512 threads (8 waves x 32 q/wave)
// LDS: 3x16KB K(fp8 plane-major) + 3x32KB V(bf16) = 144 KB.
__global__ __launch_bounds__(512, 2) void attn_kernel(
    const unsigned char* __restrict__ qg, const unsigned char* __restrict__ kg,
    const short* __restrict__ vp, short* __restrict__ outpB,
    float* __restrict__ statm, float* __restrict__ statl)
{
    extern __shared__ short lds[];
    short* KsBase = lds;                 // 3 x 8192 shorts
    short* VsBase = lds + 3 * 8192;      // 3 x 16384 shorts

    const int bid = blockIdx.x;
    const int p = bid & 7;
    const int qt = bid >> 3;
    const int q0 = qt * 256;
    const int tile0 = p * NT;

    const int tid = threadIdx.x;
    const int lane = tid & 63;
    const int w = tid >> 6;
    const int l31 = lane & 31;
    const int h = lane >> 5;

    long qf8[16];
    {
        const unsigned char* qr = qg + (size_t)(q0 + w * 32 + l31) * DD + h * 8;
        #pragma unroll
        for (int kt = 0; kt < 16; ++kt)
            qf8[kt] = __builtin_bit_cast(long, *reinterpret_cast<const u32x2*>(qr + kt * 16));
    }

    int koff[2], jdstK[2], voff[4], jdstV[4];
    #pragma unroll
    for (int i = 0; i < 2; ++i) {
        const int j = w * 2 + i;
        const int pl = 2 * j + (lane >> 5);
        koff[i] = pl * (MM * 8) + (lane & 31) * 16;
        jdstK[i] = __builtin_amdgcn_readfirstlane(j * 512);
    }
    #pragma unroll
    for (int i = 0; i < 4; ++i) {
        const int j = w * 4 + i;
        const int d = j * 8 + (lane >> 3);
        const int cl = ((lane & 7) - (d & 7)) & 7;
        voff[i] = d * 64 + (cl << 3);
        jdstV[i] = __builtin_amdgcn_readfirstlane(j * 512);
    }

    f32x16 o[8];
    #pragma unroll
    for (int dt = 0; dt < 8; ++dt)
        #pragma unroll
        for (int i = 0; i < 16; ++i) o[dt][i] = 0.f;
    float mrun = -1e30f, lrun = 0.f;
    bf16x8 pb[4];

    #pragma unroll
    for (int i = 0; i < 2; ++i)
        GLL16(kg + (size_t)tile0 * 512 + koff[i], KsBase + jdstK[i]);
    #pragma unroll
    for (int i = 0; i < 4; ++i)
        GLL16(vp + (size_t)tile0 * 16384 + voff[i], VsBase + jdstV[i]);
    #pragma unroll
    for (int i = 0; i < 2; ++i)
        GLL16(kg + (size_t)(tile0 + 1) * 512 + koff[i], KsBase + 8192 + jdstK[i]);
    asm volatile("s_waitcnt vmcnt(6)\n\ts_barrier" ::: "memory");

    // ================= t = 0 (peeled: QK only) =================
    {
        const char* kb = (const char*)KsBase;
        #pragma unroll
        for (int i = 0; i < 4; ++i)
            GLL16(vp + (size_t)(tile0 + 1) * 16384 + voff[i], VsBase + 16384 + jdstV[i]);
        #pragma unroll
        for (int i = 0; i < 2; ++i)
            GLL16(kg + (size_t)(tile0 + 2) * 512 + koff[i], KsBase + 2 * 8192 + jdstK[i]);

        f32x16 sL, sH;
        #pragma unroll
        for (int i = 0; i < 16; ++i) { sL[i] = 0.f; sH[i] = 0.f; }
        __builtin_amdgcn_s_setprio(1);
        #pragma unroll
        for (int kt = 0; kt < 16; ++kt) {
            const int gb = (kt * 2 + h) * 512 + l31 * 8;
            long aL = __builtin_bit_cast(long, *reinterpret_cast<const u32x2*>(kb + gb));
            long aH = __builtin_bit_cast(long, *reinterpret_cast<const u32x2*>(kb + gb + 256));
            sL = __builtin_amdgcn_mfma_f32_32x32x16_fp8_fp8(aL, qf8[kt], sL, 0, 0, 0);
            sH = __builtin_amdgcn_mfma_f32_32x32x16_fp8_fp8(aH, qf8[kt], sH, 0, 0, 0);
        }
        __builtin_amdgcn_s_setprio(0);

        float mx;
        {
            float a0 = fmaxf(fmaxf(sL[0], sL[1]), fmaxf(sL[2], sL[3]));
            float a1 = fmaxf(fmaxf(sL[4], sL[5]), fmaxf(sL[6], sL[7]));
            float a2 = fmaxf(fmaxf(sL[8], sL[9]), fmaxf(sL[10], sL[11]));
            float a3 = fmaxf(fmaxf(sL[12], sL[13]), fmaxf(sL[14], sL[15]));
            float b0 = fmaxf(fmaxf(sH[0], sH[1]), fmaxf(sH[2], sH[3]));
            float b1 = fmaxf(fmaxf(sH[4], sH[5]), fmaxf(sH[6], sH[7]));
            float b2 = fmaxf(fmaxf(sH[8], sH[9]), fmaxf(sH[10], sH[11]));
            float b3 = fmaxf(fmaxf(sH[12], sH[13]), fmaxf(sH[14], sH[15]));
            mx = fmaxf(fmaxf(fmaxf(a0, a1), fmaxf(a2, a3)),
                       fmaxf(fmaxf(b0, b1), fmaxf(b2, b3)));
            mx = fmaxf(mx, __shfl_xor(mx, 32));
        }
        mrun = mx;
        const float msc = -mrun * SCALE_C;
        #pragma unroll
        for (int i = 0; i < 16; ++i) {
            sL[i] = __builtin_amdgcn_exp2f(fmaf(sL[i], SCALE_C, msc));
            sH[i] = __builtin_amdgcn_exp2f(fmaf(sH[i], SCALE_C, msc));
        }
        {
            float r0 = ((sL[0] + sL[1]) + (sL[2] + sL[3])) + ((sL[4] + sL[5]) + (sL[6] + sL[7]));
            float r1 = ((sL[8] + sL[9]) + (sL[10] + sL[11])) + ((sL[12] + sL[13]) + (sL[14] + sL[15]));
            float r2 = ((sH[0] + sH[1]) + (sH[2] + sH[3])) + ((sH[4] + sH[5]) + (sH[6] + sH[7]));
            float r3 = ((sH[8] + sH[9]) + (sH[10] + sH[11])) + ((sH[12] + sH[13]) + (sH[14] + sH[15]));
            float rs = (r0 + r1) + (r2 + r3);
            rs += __shfl_xor(rs, 32);
            lrun += rs;
        }
        #pragma unroll
        for (int half = 0; half < 2; ++half) {
            const f32x16& sv = half ? sH : sL;
            #pragma unroll
            for (int g = 0; g < 2; ++g) {
                u32 pa = cvtpk(sv[g * 8 + 0], sv[g * 8 + 1]);
                u32 pbq = cvtpk(sv[g * 8 + 2], sv[g * 8 + 3]);
                u32 pc = cvtpk(sv[g * 8 + 4], sv[g * 8 + 5]);
                u32 pd = cvtpk(sv[g * 8 + 6], sv[g * 8 + 7]);
                const u32 xa = (u32)__shfl_xor((int)pa, 32);
                const u32 xb = (u32)__shfl_xor((int)pbq, 32);
                const u32 xc = (u32)__shfl_xor((int)pc, 32);
                const u32 xd = (u32)__shfl_xor((int)pd, 32);
                u32x4 bb;
                bb[0] = h ? xc : pa;
                bb[1] = h ? xd : pbq;
                bb[2] = h ? pc : xa;
                bb[3] = h ? pd : xb;
                pb[half * 2 + g] = __builtin_bit_cast(bf16x8, bb);
            }
        }
        asm volatile("s_waitcnt vmcnt(6)\n\ts_barrier" ::: "memory");
    }

    // ================= main loop t = 1 .. NT-1 =================
    int cur = 1;
    #pragma unroll 1
    for (int t = 1; t < NT; ++t) {
        const char* kb = (const char*)(KsBase + cur * 8192);
        const int vprev = (cur == 0) ? 2 : cur - 1;
        const char* vbp = (const char*)(VsBase + vprev * 16384);

        if (t + 1 < NT) {
            const int vw = (cur == 2) ? 0 : cur + 1;
            const size_t tb = (size_t)(tile0 + t + 1) * 16384;
            short* vd = VsBase + vw * 16384;
            #pragma unroll
            for (int i = 0; i < 4; ++i) GLL16(vp + tb + voff[i], vd + jdstV[i]);
        }
        if (t + 2 < NT) {
            const size_t tb = (size_t)(tile0 + t + 2) * 512;
            short* kd = KsBase + vprev * 8192;
            #pragma unroll
            for (int i = 0; i < 2; ++i) GLL16(kg + tb + koff[i], kd + jdstK[i]);
        }

        f32x16 sL, sH;
        #pragma unroll
        for (int i = 0; i < 16; ++i) { sL[i] = 0.f; sH[i] = 0.f; }
        __builtin_amdgcn_s_setprio(1);
        #pragma unroll
        for (int kt = 0; kt < 16; ++kt) {
            const int gb = (kt * 2 + h) * 512 + l31 * 8;
            long aL = __builtin_bit_cast(long, *reinterpret_cast<const u32x2*>(kb + gb));
            long aH = __builtin_bit_cast(long, *reinterpret_cast<const u32x2*>(kb + gb + 256));
            sL = __builtin_amdgcn_mfma_f32_32x32x16_fp8_fp8(aL, qf8[kt], sL, 0, 0, 0);
            sH = __builtin_amdgcn_mfma_f32_32x32x16_fp8_fp8(aH, qf8[kt], sH, 0, 0, 0);
            {
                const int j = 2 * kt;
                const int dt = j & 7, ks = j >> 3;
                const int d = dt * 32 + l31;
                bf16x8 av = *reinterpret_cast<const bf16x8*>(
                    vbp + d * 128 + (((2 * ks + h + (d & 7)) & 7) << 4));
                o[dt] = __builtin_amdgcn_mfma_f32_32x32x16_bf16(av, pb[ks], o[dt], 0, 0, 0);
            }
            {
                const int j = 2 * kt + 1;
                const int dt = j & 7, ks = j >> 3;
                const int d = dt * 32 + l31;
                bf16x8 av = *reinterpret_cast<const bf16x8*>(
                    vbp + d * 128 + (((2 * ks + h + (d & 7)) & 7) << 4));
                o[dt] = __builtin_amdgcn_mfma_f32_32x32x16_bf16(av, pb[ks], o[dt], 0, 0, 0);
            }
        }
        __builtin_amdgcn_s_setprio(0);

        float mx;
        {
            float a0 = fmaxf(fmaxf(sL[0], sL[1]), fmaxf(sL[2], sL[3]));
            float a1 = fmaxf(fmaxf(sL[4], sL[5]), fmaxf(sL[6], sL[7]));
            float a2 = fmaxf(fmaxf(sL[8], sL[9]), fmaxf(sL[10], sL[11]));
            float a3 = fmaxf(fmaxf(sL[12], sL[13]), fmaxf(sL[14], sL[15]));
            float b0 = fmaxf(fmaxf(sH[0], sH[1]), fmaxf(sH[2], sH[3]));
            float b1 = fmaxf(fmaxf(sH[4], sH[5]), fmaxf(sH[6], sH[7]));
            float b2 = fmaxf(fmaxf(sH[8], sH[9]), fmaxf(sH[10], sH[11]));
            float b3 = fmaxf(fmaxf(sH[12], sH[13]), fmaxf(sH[14], sH[15]));
            mx = fmaxf(fmaxf(fmaxf(a0, a1), fmaxf(a2, a3)),
                       fmaxf(fmaxf(b0, b1), fmaxf(b2, b3)));
            mx = fmaxf(mx, __shfl_xor(mx, 32));
        }
        if (__any(mx > mrun + RAW_THR)) {
            const float mn = fmaxf(mrun, mx);
            const float al = __builtin_amdgcn_exp2f((mrun - mn) * SCALE_C);
            mrun = mn;
            lrun *= al;
            #pragma unroll
            for (int dt = 0; dt < 8; ++dt)
                #pragma unroll
                for (int i = 0; i < 16; ++i) o[dt][i] *= al;
        }
        const float msc = -mrun * SCALE_C;
        #pragma unroll
        for (int i = 0; i < 16; ++i) {
            sL[i] = __builtin_amdgcn_exp2f(fmaf(sL[i], SCALE_C, msc));
            sH[i] = __builtin_amdgcn_exp2f(fmaf(sH[i], SCALE_C, msc));
        }
        {
            float r0 = ((sL[0] + sL[1]) + (sL[2] + sL[3])) + ((sL[4] + sL[5]) + (sL[6] + sL[7]));
            float r1 = ((sL[8] + sL[9]) + (sL[10] + sL[11])) + ((sL[12] + sL[13]) + (sL[14] + sL[15]));
            float r2 = ((sH[0] + sH[1]) + (sH[2] + sH[3])) + ((sH[4] + sH[5]) + (sH[6] + sH[7]));
            float r3 = ((sH[8] + sH[9]) + (sH[10] + sH[11])) + ((sH[12] + sH[13]) + (sH[14] + sH[15]));
            float rs = (r0 + r1) + (r2 + r3);
            rs += __shfl_xor(rs, 32);
            lrun += rs;
        }
        #pragma unroll
        for (int half = 0; half < 2; ++half) {
            const f32x16& sv = half ? sH : sL;
            #pragma unroll
            for (int g = 0; g < 2; ++g) {
                u32 pa = cvtpk(sv[g * 8 + 0], sv[g * 8 + 1]);
                u32 pbq = cvtpk(sv[g * 8 + 2], sv[g * 8 + 3]);
                u32 pc = cvtpk(sv[g * 8 + 4], sv[g * 8 + 5]);
                u32 pd = cvtpk(sv[g * 8 + 6], sv[g * 8 + 7]);
                const u32 xa = (u32)__shfl_xor((int)pa, 32);
                const u32 xb = (u32)__shfl_xor((int)pbq, 32);
                const u32 xc = (u32)__shfl_xor((int)pc, 32);
                const u32 xd = (u32)__shfl_xor((int)pd, 32);
                u32x4 bb;
                bb[0] = h ? xc : pa;
                bb[1] = h ? xd : pbq;
                bb[2] = h ? pc : xa;
                bb[3] = h ? pd : xb;
                pb[half * 2 + g] = __builtin_bit_cast(bf16x8, bb);
            }
        }

        if (t + 2 < NT) {
            asm volatile("s_waitcnt vmcnt(6)\n\ts_barrier" ::: "memory");
        } else if (t + 1 < NT) {
            asm volatile("s_waitcnt vmcnt(4)\n\ts_barrier" ::: "memory");
        } else {
            asm volatile("s_waitcnt vmcnt(0)\n\ts_barrier" ::: "memory");
        }
        cur = (cur == 2) ? 0 : cur + 1;
    }

    // ---- final PV(NT-1) ----
    {
        const char* vb = (const char*)(VsBase + ((NT - 1) % 3) * 16384);
        __builtin_amdgcn_s_setprio(1);
        #pragma unroll
        for (int dt = 0; dt < 8; ++dt) {
            const int d = dt * 32 + l31;
            const char* rbase = vb + d * 128;
            const int rot = d & 7;
            bf16x8 a0 = *reinterpret_cast<const bf16x8*>(rbase + (((0 + h + rot) & 7) << 4));
            bf16x8 a1 = *reinterpret_cast<const bf16x8*>(rbase + (((2 + h + rot) & 7) << 4));
            bf16x8 a2 = *reinterpret_cast<const bf16x8*>(rbase + (((4 + h + rot) & 7) << 4));
            bf16x8 a3 = *reinterpret_cast<const bf16x8*>(rbase + (((6 + h + rot) & 7) << 4));
            o[dt] = __builtin_amdgcn_mfma_f32_32x32x16_bf16(a0, pb[0], o[dt], 0, 0, 0);
            o[dt] = __builtin_amdgcn_mfma_f32_32x32x16_bf16(a1, pb[1], o[dt], 0, 0, 0);
            o[dt] = __builtin_amdgcn_mfma_f32_32x32x16_bf16(a2, pb[2], o[dt], 0, 0, 0);
            o[dt] = __builtin_amdgcn_mfma_f32_32x32x16_bf16(a3, pb[3], o[dt], 0, 0, 0);
        }
        __builtin_amdgcn_s_setprio(0);
    }

    const int qc = q0 + w * 32 + l31;
    #pragma unroll
    for (int dt = 0; dt < 8; ++dt) {
        #pragma unroll
        for (int i = 0; i < 16; i += 2) {
            const u32 two = cvtpk(o[dt][i], o[dt][i + 1]);
            const int dg = dt * 32 + (i & 3) + 8 * (i >> 2) + 4 * h;
            outpB[((size_t)p * DD + dg) * NN + qc] = (short)(two & 0xFFFFu);
            outpB[((size_t)p * DD + dg + 1) * NN + qc] = (short)(two >> 16);
        }
    }
    if (h == 0) {
        statm[(size_t)p * NN + qc] = mrun;
        statl[(size_t)p * NN + qc] = lrun;
    }
}

// ---------------- combine [frozen R13] ----------------
__global__ __launch_bounds__(1024) void combine_kernel(
    const short* __restrict__ outpB, const float* __restrict__ statm,
    const float* __restrict__ statl, float* __restrict__ out)
{
    __shared__ float Wn[NPART][64];
    __shared__ float Ot[64][DD + 2];

    const int q0 = blockIdx.x * 64;
    const int tid = threadIdx.x;

    if (tid < 64) {
        const int q = q0 + tid;
        float mv[NPART], lv[NPART];
        float mM = -1e30f;
        #pragma unroll
        for (int p = 0; p < NPART; ++p) {
            mv[p] = statm[(size_t)p * NN + q];
            lv[p] = statl[(size_t)p * NN + q];
            mM = fmaxf(mM, mv[p]);
        }
        float L = 0.f;
        float wg[NPART];
        #pragma unroll
        for (int p = 0; p < NPART; ++p) {
            wg[p] = exp2f((mv[p] - mM) * SCALE_C);
            L += wg[p] * lv[p];
        }
        const float inv = 1.0f / L;
        #pragma unroll
        for (int p = 0; p < NPART; ++p) Wn[p][tid] = wg[p] * inv;
    }
    __syncthreads();

    {
        const int pr = tid & 31;
        const int d0 = tid >> 5;
        #pragma unroll 2
        for (int d = d0; d < DD; d += 32) {
            float a0 = 0.f, a1 = 0.f;
            #pragma unroll
            for (int p = 0; p < NPART; ++p) {
                const u32 two = *reinterpret_cast<const u32*>(
                    &outpB[((size_t)p * DD + d) * NN + q0 + pr * 2]);
                a0 += Wn[p][pr * 2] * __builtin_bit_cast(float, two << 16);
                a1 += Wn[p][pr * 2 + 1] * __builtin_bit_cast(float, two & 0xFFFF0000u);
            }
            Ot[pr * 2][d] = a0;
            Ot[pr * 2 + 1][d] = a1;
        }
    }
    __syncthreads();

    {
        const int qq = tid >> 4;
        const int c = tid & 15;
        #pragma unroll
        for (int j = 0; j < 4; ++j) {
            const int d = c * 16 + j * 4;
            *reinterpret_cast<f32x4*>(&out[(size_t)(q0 + qq) * DD + d]) =
                *reinterpret_cast<const f32x4*>(&Ot[qq][d]);
        }
    }
}

extern "C" void kernel_launch(void* const* d_in, const int* in_sizes, int n_in,
                              void* d_out, int out_size, void* d_ws, size_t ws_size,
                              hipStream_t stream) {
    const float* xq  = (const float*)d_in[0];
    const float* xkv = (const float*)d_in[1];
    const float* Wq  = (const float*)d_in[2];
    const float* bq  = (const float*)d_in[3];
    const float* Wk  = (const float*)d_in[4];
    const float* bk  = (const float*)d_in[5];
    const float* Wv  = (const float*)d_in[6];
    const float* bv  = (const float*)d_in[7];
    float* out = (float*)d_out;

    char* ws = (char*)d_ws;
    unsigned char* qb8 = (unsigned char*)(ws);
    unsigned char* kb8 = (unsigned char*)(ws + ((size_t)4 << 20));
    short* vpb = (short*)(ws + ((size_t)8 << 20));
    short* outpB = (short*)(ws + ((size_t)12 << 20));
    float* sm = (float*)(ws + ((size_t)12 << 20) + (size_t)NPART * NN * DD * 2);
    float* sl = sm + (size_t)NPART * NN;

    hipFuncSetAttribute(reinterpret_cast<const void*>(attn_kernel),
                        hipFuncAttributeMaxDynamicSharedMemorySize, 147456);

    proj_kernel<<<1024, 256, 0, stream>>>(xq, xkv, Wq, bq, Wk, bk, Wv, bv, qb8, kb8, vpb);
    attn_kernel<<<256, 512, 147456, stream>>>(qb8, kb8, vpb, outpB, sm, sl);
    combine_kernel<<<NN / 64, 1024, 0, stream>>>(outpB, sm, sl, out);
}